// Round 7
// baseline (102.841 us; speedup 1.0000x reference)
//
#include <hip/hip_runtime.h>

#define BLK 512
#define MT 32            // mfma tile edge
#define IA 2             // A-frags per wave
#define IB 512           // rows per block = 8 waves * 32 * IA
#define TJQ 512          // q points per LDS chunk
#define SJ 8             // j-slices per batch -> grid (32,8,2) = 512 blocks

typedef __attribute__((ext_vector_type(8))) short short8;
typedef __attribute__((ext_vector_type(16))) float f32x16;

__device__ __forceinline__ unsigned int fmap(float f) {
  unsigned int b = __float_as_uint(f);
  return (b & 0x80000000u) ? ~b : (b | 0x80000000u);
}
__device__ __forceinline__ float funmap(unsigned int u) {
  return __uint_as_float((u & 0x80000000u) ? (u ^ 0x80000000u) : ~u);
}
__device__ __forceinline__ unsigned short f2bf(float f) {
  unsigned int u = __float_as_uint(f);
  u += 0x7FFFu + ((u >> 16) & 1u);
  return (unsigned short)(u >> 16);
}
__device__ __forceinline__ float bf2f(unsigned short h) {
  return __uint_as_float(((unsigned int)h) << 16);
}
__device__ __forceinline__ unsigned int pk(unsigned short a, unsigned short b) {
  return (unsigned int)a | ((unsigned int)b << 16);
}

union FragU { uint4 u; short8 s; };

// Two MFMAs into VGPR destinations ("=&v" on the gfx950 unified file).
// s_nop 7,7,1 = 18 cyc covers MFMA D-write -> VALU-read (validated R11,
// absmax margin 0). The c operand now carries |p_i|^2 per row (npc), making
// D = |p|^2 + |q|^2 - 2p.q directly — free adds for the col-min path, and
// exactly equivalent for the row path (fp32 add is monotone).
#define MFMA2(d0, d1, a, b0, b1, c)                                    \
  asm("v_mfma_f32_32x32x16_bf16 %0, %2, %3, %5\n\t"                    \
      "v_mfma_f32_32x32x16_bf16 %1, %2, %4, %5\n\t"                    \
      "s_nop 7\n\t"                                                    \
      "s_nop 7\n\t"                                                    \
      "s_nop 1"                                                        \
      : "=&v"(d0), "=&v"(d1)                                           \
      : "v"(a), "v"(b0), "v"(b1), "v"(c))

// v_min3 with ALL operands pinned to arch VGPRs (R11: prevents AGPR
// allocation of accumulators and the a<->v copy tax).
#define MIN3(acc, x, y)                                                \
  asm("v_min3_f32 %0, %0, %1, %2" : "+v"(acc) : "v"(x), "v"(y))

// R19: symmetric one-pass. dir=0 and dir=1 computed the SAME distance
// matrix transposed — half the MFMA work was redundant. This kernel
// computes F = |p|^2 + |q|^2 - 2p.q ONCE (|p|^2 via the MFMA C-operand)
// and reduces BOTH axes: row-mins (dist1, pc1->pc2) exactly as before;
// col-mins (dist2, pc2->pc1) via per-lane min3 trees + shfl_xor(32) +
// LDS atomicMin into scol[512] per chunk, flushed to global per chunk.
// Rounds per block halve (nch 8->4 worth of total work); the per-round
// wall (invariant across R12-R18) now buys half as many rounds.
// Fragments / k-slot layout / MFMA2+nops / min3 — untouched (R5-R11).
__global__ __launch_bounds__(BLK, 4) void cl_mfma(
    const float* __restrict__ A, const float* __restrict__ Bp,
    float* __restrict__ pm, unsigned int* __restrict__ gc,
    float* __restrict__ outp, int N, int jslice) {
  __shared__ uint4 sA[2][IB];       // A-vec halves [g][row]    16 KB
  __shared__ uint4 sB[2][TJQ];      // B-vec halves [g][point]  16 KB
  __shared__ float sNP[IB];         // |p|^2 per row             2 KB
  __shared__ unsigned int scol[TJQ];// per-chunk col-min (fmap)  2 KB

  const int b = blockIdx.z;
  const float* __restrict__ P = A;   // pc1 rows
  const float* __restrict__ Q = Bp;  // pc2 cols
  unsigned int* __restrict__ gcb = gc + (size_t)b * N;

  const int t = threadIdx.x;

  // zero the scalar output here (stream order puts cl_reduce2 after all
  // cl_mfma blocks) — saves the out-memset launch node. (validated R16)
  if (blockIdx.x == 0 && blockIdx.y == 0 && blockIdx.z == 0 && t == 0)
    *outp = 0.0f;

  const int ib0 = blockIdx.x * IB;
  const int jbase = blockIdx.y * jslice;
  const size_t boff = (size_t)b * 3 * N;
  const size_t pbase = ((size_t)b * gridDim.y + blockIdx.y) * (size_t)N;
  const unsigned short one = 0x3F80u;  // bf16(1.0)

  // ---- stage A-vectors + |p|^2 (once) ----
  {
    int i = ib0 + t;
    float x = P[boff + i], y = P[boff + N + i], zz = P[boff + 2 * N + i];
    float ax = -2.f * x, ay = -2.f * y, az = -2.f * zz;
    unsigned short hx = f2bf(ax), hy = f2bf(ay), hz = f2bf(az);
    unsigned short lx = f2bf(ax - bf2f(hx)), ly = f2bf(ay - bf2f(hy)),
                   lz = f2bf(az - bf2f(hz));
    sA[0][t] = make_uint4(pk(hx, hy), pk(hz, lx), pk(ly, lz), pk(hx, hy));
    sA[1][t] = make_uint4(pk(hz, lx), pk(ly, lz), pk(one, one), pk(one, 0));
    sNP[t] = fmaf(zz, zz, fmaf(y, y, x * x));
  }
  __syncthreads();

  const int w = t >> 6, l = t & 63, m = l & 31, g = l >> 5;
  FragU a0u, a1u;
  a0u.u = sA[g][w * (MT * IA) + m];        // rows w*64 + 0..31
  a1u.u = sA[g][w * (MT * IA) + MT + m];   // rows w*64 + 32..63
  const short8 af0 = a0u.s, af1 = a1u.s;
  const uint4* __restrict__ sBg = sB[g];

  // per-reg |p|^2 for the MFMA C-operand.
  // C/D layout (m74/m101): col=lane&31, row=(r&3)+8*(r>>2)+4*(lane>>5)
  f32x16 npc0, npc1;
#pragma unroll
  for (int r = 0; r < 16; ++r) {
    int row = (r & 3) + 8 * (r >> 2) + 4 * g;
    npc0[r] = sNP[w * (MT * IA) + row];
    npc1[r] = sNP[w * (MT * IA) + MT + row];
  }

  float run0[16], run1[16];
#pragma unroll
  for (int r = 0; r < 16; ++r) { run0[r] = 3.0e38f; run1[r] = 3.0e38f; }

  const int nch = jslice / TJQ;  // 4
  float qx = Q[boff + jbase + t];
  float qy = Q[boff + N + jbase + t];
  float qz = Q[boff + 2 * N + jbase + t];

  for (int ch = 0; ch < nch; ++ch) {
    unsigned short hx = f2bf(qx), hy = f2bf(qy), hz = f2bf(qz);
    unsigned short lx = f2bf(qx - bf2f(hx)), ly = f2bf(qy - bf2f(hy)),
                   lz = f2bf(qz - bf2f(hz));
    float nq = fmaf(qz, qz, fmaf(qy, qy, qx * qx));
    unsigned short nh = f2bf(nq);
    float r1 = nq - bf2f(nh);
    unsigned short nm = f2bf(r1);
    unsigned short nl = f2bf(r1 - bf2f(nm));
    uint4 b0s = make_uint4(pk(hx, hy), pk(hz, hx), pk(hy, hz), pk(lx, ly));
    uint4 b1s = make_uint4(pk(lz, lx), pk(ly, lz), pk(nh, nm), pk(nl, 0));

    __syncthreads();  // prev chunk fully consumed (incl. scol atomics)

    if (ch > 0) {  // flush previous chunk's col partials (own slot only)
      atomicMin(&gcb[jbase + (ch - 1) * TJQ + t], scol[t]);
    }
    scol[t] = 0xFFFFFFFFu;

    sB[0][t] = b0s;
    sB[1][t] = b1s;
    {  // prefetch next chunk's q
      int jn = (ch + 1 < nch) ? (jbase + (ch + 1) * TJQ + t) : (jbase + t);
      qx = Q[boff + jn];
      qy = Q[boff + N + jn];
      qz = Q[boff + 2 * N + jn];
    }
    __syncthreads();

#pragma unroll
    for (int jt = 0; jt < TJQ / MT; jt += 2) {
      FragU ba, bb;
      ba.u = sBg[(jt + 0) * MT + m];
      bb.u = sBg[(jt + 1) * MT + m];
      f32x16 d0, d1;
      MFMA2(d0, d1, af0, ba.s, bb.s, npc0);
#pragma unroll
      for (int r = 0; r < 16; ++r) MIN3(run0[r], d0[r], d1[r]);
      // col partial trees over af0's rows (2 chains per tile; d0/d1 die here)
      float ca0 = fminf(d0[0], d0[1]), cb0 = fminf(d0[2], d0[3]);
      float ca1 = fminf(d1[0], d1[1]), cb1 = fminf(d1[2], d1[3]);
#pragma unroll
      for (int r = 4; r < 16; r += 4) {
        MIN3(ca0, d0[r], d0[r + 1]); MIN3(cb0, d0[r + 2], d0[r + 3]);
        MIN3(ca1, d1[r], d1[r + 1]); MIN3(cb1, d1[r + 2], d1[r + 3]);
      }
      ca0 = fminf(ca0, cb0);
      ca1 = fminf(ca1, cb1);
      f32x16 d2, d3;
      MFMA2(d2, d3, af1, ba.s, bb.s, npc1);
#pragma unroll
      for (int r = 0; r < 16; ++r) MIN3(run1[r], d2[r], d3[r]);
      float ca2 = fminf(d2[0], d2[1]), cb2 = fminf(d2[2], d2[3]);
      float ca3 = fminf(d3[0], d3[1]), cb3 = fminf(d3[2], d3[3]);
#pragma unroll
      for (int r = 4; r < 16; r += 4) {
        MIN3(ca2, d2[r], d2[r + 1]); MIN3(cb2, d2[r + 2], d2[r + 3]);
        MIN3(ca3, d3[r], d3[r + 1]); MIN3(cb3, d3[r + 2], d3[r + 3]);
      }
      float va = fminf(fminf(ca2, cb2), ca0);   // tile ba, 32 rows (this half)
      float vb = fminf(fminf(ca3, cb3), ca1);   // tile bb
      va = fminf(va, __shfl_xor(va, 32));       // merge g-halves -> 64 rows
      vb = fminf(vb, __shfl_xor(vb, 32));
      if (g == 0) {
        atomicMin(&scol[(jt + 0) * MT + m], fmap(va));
        atomicMin(&scol[(jt + 1) * MT + m], fmap(vb));
      }
    }
  }

  __syncthreads();
  atomicMin(&gcb[jbase + (nch - 1) * TJQ + t], scol[t]);  // final flush

  // ---- row epilogue: min across 32 cols -> pm (np already included) ----
#pragma unroll
  for (int r = 0; r < 16; ++r) {
    float v0 = run0[r], v1 = run1[r];
#pragma unroll
    for (int sh = 1; sh <= 16; sh <<= 1) {
      v0 = fminf(v0, __shfl_xor(v0, sh));
      v1 = fminf(v1, __shfl_xor(v1, sh));
    }
    if (m == 0) {
      int row = (r & 3) + 8 * (r >> 2) + 4 * g;
      int il0 = w * (MT * IA) + row;
      int il1 = il0 + MT;
      pm[pbase + ib0 + il0] = v0;
      pm[pbase + ib0 + il1] = v1;
    }
  }
}

// Final reduce: rows part = min over SJ per-slice partials (pm, 512 KB);
// cols part = funmap(gc, 128 KB). Sum both, divide by 2*B*N.
__global__ __launch_bounds__(256) void cl_reduce2(
    const float* __restrict__ pm, const unsigned int* __restrict__ gc,
    float* __restrict__ out, int N, int sj) {
  const int t = threadIdx.x;
  const int rows = 2 * N;        // B*N row items
  const int totalItems = 4 * N;  // + B*N col items
  int gid = blockIdx.x * 256 + t;
  const int gstride = gridDim.x * 256;
  double s = 0.0;
  for (int idx = gid; idx < totalItems; idx += gstride) {
    float v;
    if (idx < rows) {
      int bb = idx / N, i = idx - bb * N;
      const float* p = pm + ((size_t)bb * sj) * N + i;
      float mv = p[0];
      for (int by = 1; by < sj; ++by) mv = fminf(mv, p[(size_t)by * N]);
      v = mv;
    } else {
      v = funmap(gc[idx - rows]);
    }
    s += (double)v;
  }
  for (int off = 32; off > 0; off >>= 1) s += __shfl_down(s, off, 64);
  __shared__ double sw[4];
  if ((t & 63) == 0) sw[t >> 6] = s;
  __syncthreads();
  if (t == 0) {
    double tot = sw[0] + sw[1] + sw[2] + sw[3];
    atomicAdd(out, (float)(tot / (double)totalItems));
  }
}

extern "C" void kernel_launch(void* const* d_in, const int* in_sizes, int n_in,
                              void* d_out, int out_size, void* d_ws, size_t ws_size,
                              hipStream_t stream) {
  const float* in_pc = (const float*)d_in[0];
  const float* tgt_pc = (const float*)d_in[1];
  const int B = 2, N = 16384;
  float* out = (float*)d_out;

  // workspace: pm [B][SJ][N] floats (512 KB) + gc [B][N] uints (128 KB).
  // R18 confirmed ws_size >= 1 MB (pm path ran there).
  float* pm = (float*)d_ws;
  unsigned int* gc =
      (unsigned int*)((char*)d_ws + (size_t)B * SJ * N * sizeof(float));
  hipMemsetAsync(gc, 0xFF, (size_t)B * N * sizeof(unsigned int), stream);

  const int jslice = N / SJ;             // 2048
  dim3 grid(N / IB, SJ, B);              // (32,8,2) = 512 blocks x 512 thr
  cl_mfma<<<grid, dim3(BLK), 0, stream>>>(in_pc, tgt_pc, pm, gc, out, N, jslice);

  cl_reduce2<<<dim3(64), dim3(256), 0, stream>>>(pm, gc, out, N, SJ);
}